// Round 1
// baseline (143.237 us; speedup 1.0000x reference)
//
#include <hip/hip_runtime.h>
#include <hip/hip_bf16.h>

#define B_ 8
#define T_ 2048
#define C_ 1024
#define H_ 64

typedef __bf16 bf16x8 __attribute__((ext_vector_type(8)));
typedef float f32x4 __attribute__((ext_vector_type(4)));

__device__ __forceinline__ unsigned short f2bf(float f) {
    union { float f; unsigned u; } v; v.f = f;
    unsigned u = v.u;
    u += 0x7fffu + ((u >> 16) & 1u);   // round-to-nearest-even
    return (unsigned short)(u >> 16);
}

// ---------- kernel 0: transpose+convert weights into wt[192][1024] bf16 ----------
// column order: [0,64) = w_k, [64,128) = w_q, [128,192) = w_v
__global__ void wtrans_kernel(const float* __restrict__ wk,
                              const float* __restrict__ wq,
                              const float* __restrict__ wv,
                              unsigned short* __restrict__ wt) {
    int idx = blockIdx.x * 256 + threadIdx.x;   // 192*1024 total
    int n = idx >> 10, k = idx & 1023;
    int m = n >> 6, c = n & 63;
    const float* w = (m == 0) ? wk : (m == 1) ? wq : wv;
    wt[idx] = f2bf(w[k * 64 + c]);
}

// ---------- kernel 1: fused QKV projection (bf16 MFMA, f32 accum) ----------
// outputs: kh[16384][64] bf16, qh[16384][64] bf16 (pre-scaled by C^-0.5),
//          vt[B][64][2048] bf16 (v transposed for PV A-operand reads)
__global__ __launch_bounds__(256) void qkv_kernel(const float* __restrict__ x,
        const unsigned short* __restrict__ wt,
        unsigned short* __restrict__ kh,
        unsigned short* __restrict__ qh,
        unsigned short* __restrict__ vt) {
    __shared__ unsigned short xs[64][72];    // [row][k] bf16, padded
    __shared__ unsigned short wst[192][72];  // [col][k] bf16, padded
    const int tid = threadIdx.x;
    const int wid = tid >> 6, lane = tid & 63;
    const int lq = lane & 15, g = lane >> 4;
    const int row0 = blockIdx.x * 64;

    f32x4 acc[12] = {};

    for (int k0 = 0; k0 < C_; k0 += 64) {
        // stage x tile 64x64 -> bf16
        #pragma unroll
        for (int rep = 0; rep < 4; ++rep) {
            int idx = rep * 1024 + tid * 4;
            int r = idx >> 6, kk = idx & 63;
            const float4 xv = *(const float4*)(x + (size_t)(row0 + r) * C_ + k0 + kk);
            ushort4 pv;
            pv.x = f2bf(xv.x); pv.y = f2bf(xv.y); pv.z = f2bf(xv.z); pv.w = f2bf(xv.w);
            *(ushort4*)&xs[r][kk] = pv;
        }
        // stage wt tile 192x64 (already bf16, contiguous in k)
        #pragma unroll
        for (int rep = 0; rep < 6; ++rep) {
            int idx = rep * 256 + tid;
            int col = idx >> 3, k8 = (idx & 7) * 8;
            *(uint4*)&wst[col][k8] = *(const uint4*)(wt + (size_t)col * C_ + k0 + k8);
        }
        __syncthreads();
        #pragma unroll
        for (int ks = 0; ks < 2; ++ks) {
            bf16x8 a = *(const bf16x8*)&xs[wid * 16 + lq][ks * 32 + g * 8];
            #pragma unroll
            for (int j = 0; j < 12; ++j) {
                bf16x8 b = *(const bf16x8*)&wst[j * 16 + lq][ks * 32 + g * 8];
                acc[j] = __builtin_amdgcn_mfma_f32_16x16x32_bf16(a, b, acc[j], 0, 0, 0);
            }
        }
        __syncthreads();
    }
    // epilogue: D layout col=lane&15, row=(lane>>4)*4+reg
    #pragma unroll
    for (int j = 0; j < 12; ++j) {
        int col = j * 16 + lq;
        int m = col >> 6, h = col & 63;
        #pragma unroll
        for (int r = 0; r < 4; ++r) {
            int grow = row0 + wid * 16 + g * 4 + r;
            float val = acc[j][r];
            if (m == 0) {
                kh[(size_t)grow * H_ + h] = f2bf(val);
            } else if (m == 1) {
                qh[(size_t)grow * H_ + h] = f2bf(val * 0.03125f);  // C^-0.5
            } else {
                int bb = grow >> 11, t = grow & (T_ - 1);
                vt[((size_t)bb * H_ + h) * T_ + t] = f2bf(val);
            }
        }
    }
}

// ---------- kernel 2: causal flash attention, 1 wave per 16 q-rows ----------
__global__ __launch_bounds__(64) void attn_kernel(const unsigned short* __restrict__ kh,
        const unsigned short* __restrict__ qh,
        const unsigned short* __restrict__ vt,
        float* __restrict__ out) {
    __shared__ unsigned short p_lds[16][40];  // [q][s] bf16, padded row 80B
    const int lane = threadIdx.x;
    const int lq = lane & 15, g = lane >> 4;
    const int bx = blockIdx.x;
    const int b = bx & 7, qi = bx >> 3;
    const int q0 = ((T_ / 16 - 1) - qi) * 16;   // heavy q-blocks launch first

    const unsigned short* khb = kh + (size_t)b * T_ * H_;
    const unsigned short* qhb = qh + (size_t)b * T_ * H_;
    const unsigned short* vtb = vt + (size_t)b * H_ * T_;

    // Q B-fragments (col=q=lane&15, k=h=(lane>>4)*8+i), h in [0,32) and [32,64)
    bf16x8 qf0 = *(const bf16x8*)(qhb + (q0 + lq) * H_ + g * 8);
    bf16x8 qf1 = *(const bf16x8*)(qhb + (q0 + lq) * H_ + 32 + g * 8);

    float m_run = -1e30f, l_run = 0.f;
    f32x4 o[4] = {};

    const int q_glob = q0 + lq;
    const int s_end = q0 + 16;
    for (int s0 = 0; s0 < s_end; s0 += 32) {
        const bool t1 = (s0 + 16) < s_end;
        // S^T = K . Q^T  (two 16-wide s tiles, K dim = h)
        f32x4 sa0 = {0.f, 0.f, 0.f, 0.f};
        f32x4 sa1 = {0.f, 0.f, 0.f, 0.f};
        {
            bf16x8 k00 = *(const bf16x8*)(khb + (s0 + lq) * H_ + g * 8);
            bf16x8 k01 = *(const bf16x8*)(khb + (s0 + lq) * H_ + 32 + g * 8);
            sa0 = __builtin_amdgcn_mfma_f32_16x16x32_bf16(k00, qf0, sa0, 0, 0, 0);
            sa0 = __builtin_amdgcn_mfma_f32_16x16x32_bf16(k01, qf1, sa0, 0, 0, 0);
        }
        if (t1) {
            bf16x8 k10 = *(const bf16x8*)(khb + (s0 + 16 + lq) * H_ + g * 8);
            bf16x8 k11 = *(const bf16x8*)(khb + (s0 + 16 + lq) * H_ + 32 + g * 8);
            sa1 = __builtin_amdgcn_mfma_f32_16x16x32_bf16(k10, qf0, sa1, 0, 0, 0);
            sa1 = __builtin_amdgcn_mfma_f32_16x16x32_bf16(k11, qf1, sa1, 0, 0, 0);
        }
        // online softmax over s (rows of S^T): per-lane q = lq, s = tile*16 + g*4 + r
        float p0[4], p1[4];
        float smax = -1e30f;
        #pragma unroll
        for (int r = 0; r < 4; ++r) {
            int sg0 = s0 + g * 4 + r;
            int sg1 = s0 + 16 + g * 4 + r;
            p0[r] = (sg0 <= q_glob) ? sa0[r] : -1e30f;
            p1[r] = (t1 && sg1 <= q_glob) ? sa1[r] : -1e30f;
            smax = fmaxf(smax, fmaxf(p0[r], p1[r]));
        }
        smax = fmaxf(smax, __shfl_xor(smax, 16));
        smax = fmaxf(smax, __shfl_xor(smax, 32));
        const float m_new = fmaxf(m_run, smax);
        const float alpha = __expf(m_run - m_new);
        float lsum = 0.f;
        #pragma unroll
        for (int r = 0; r < 4; ++r) {
            p0[r] = __expf(p0[r] - m_new);
            p1[r] = __expf(p1[r] - m_new);
            lsum += p0[r] + p1[r];
        }
        lsum += __shfl_xor(lsum, 16);
        lsum += __shfl_xor(lsum, 32);
        l_run = l_run * alpha + lsum;
        m_run = m_new;
        #pragma unroll
        for (int hc = 0; hc < 4; ++hc) o[hc] *= alpha;

        // write P^T into LDS as [q][s] bf16 (masked/inactive entries are 0)
        *(unsigned*)&p_lds[lq][g * 4]          = (unsigned)f2bf(p0[0]) | ((unsigned)f2bf(p0[1]) << 16);
        *(unsigned*)&p_lds[lq][g * 4 + 2]      = (unsigned)f2bf(p0[2]) | ((unsigned)f2bf(p0[3]) << 16);
        *(unsigned*)&p_lds[lq][16 + g * 4]     = (unsigned)f2bf(p1[0]) | ((unsigned)f2bf(p1[1]) << 16);
        *(unsigned*)&p_lds[lq][16 + g * 4 + 2] = (unsigned)f2bf(p1[2]) | ((unsigned)f2bf(p1[3]) << 16);

        // PV: O^T[h][q] += V^T[h][s] . P^T[s][q]
        bf16x8 pb = *(const bf16x8*)&p_lds[lq][g * 8];
        #pragma unroll
        for (int hc = 0; hc < 4; ++hc) {
            bf16x8 vf = *(const bf16x8*)(vtb + (size_t)(hc * 16 + lq) * T_ + s0 + g * 8);
            o[hc] = __builtin_amdgcn_mfma_f32_16x16x32_bf16(vf, pb, o[hc], 0, 0, 0);
        }
    }

    const float inv_l = 1.0f / l_run;
    float* ob = out + ((size_t)b * T_ + q0 + lq) * H_;
    #pragma unroll
    for (int hc = 0; hc < 4; ++hc)
        #pragma unroll
        for (int r = 0; r < 4; ++r)
            ob[hc * 16 + g * 4 + r] = o[hc][r] * inv_l;
}

extern "C" void kernel_launch(void* const* d_in, const int* in_sizes, int n_in,
                              void* d_out, int out_size, void* d_ws, size_t ws_size,
                              hipStream_t stream) {
    const float* x  = (const float*)d_in[0];
    const float* wk = (const float*)d_in[1];
    const float* wq = (const float*)d_in[2];
    const float* wv = (const float*)d_in[3];
    float* out = (float*)d_out;

    char* ws = (char*)d_ws;
    unsigned short* kh = (unsigned short*)(ws);                            // 2 MB
    unsigned short* qh = (unsigned short*)(ws + (size_t)2 * 1024 * 1024);  // 2 MB
    unsigned short* vt = (unsigned short*)(ws + (size_t)4 * 1024 * 1024);  // 2 MB
    unsigned short* wt = (unsigned short*)(ws + (size_t)6 * 1024 * 1024);  // 384 KB

    wtrans_kernel<<<dim3(768), dim3(256), 0, stream>>>(wk, wq, wv, wt);
    qkv_kernel<<<dim3(256), dim3(256), 0, stream>>>(x, wt, kh, qh, vt);
    attn_kernel<<<dim3(B_ * T_ / 16), dim3(64), 0, stream>>>(kh, qh, vt, out);
}

// Round 2
// 104.201 us; speedup vs baseline: 1.3746x; 1.3746x over previous
//
#include <hip/hip_runtime.h>
#include <hip/hip_bf16.h>

#define B_ 8
#define T_ 2048
#define C_ 1024
#define H_ 64

typedef __bf16 bf16x8 __attribute__((ext_vector_type(8)));
typedef float f32x4 __attribute__((ext_vector_type(4)));

__device__ __forceinline__ unsigned short f2bf(float f) {
    union { float f; unsigned u; } v; v.f = f;
    unsigned u = v.u;
    u += 0x7fffu + ((u >> 16) & 1u);   // round-to-nearest-even
    return (unsigned short)(u >> 16);
}

#define GLOAD16(g, l) __builtin_amdgcn_global_load_lds( \
    (const __attribute__((address_space(1))) void*)(g), \
    (__attribute__((address_space(3))) void*)(l), 16, 0, 0)

// ---------- kernel 0: transpose+convert weights into wt[192][1024] bf16 ----------
// column order: [0,64) = w_k, [64,128) = w_q, [128,192) = w_v
__global__ void wtrans_kernel(const float* __restrict__ wk,
                              const float* __restrict__ wq,
                              const float* __restrict__ wv,
                              unsigned short* __restrict__ wt) {
    int idx = blockIdx.x * 256 + threadIdx.x;   // 192*1024 total
    int n = idx >> 10, k = idx & 1023;
    int m = n >> 6, c = n & 63;
    const float* w = (m == 0) ? wk : (m == 1) ? wq : wv;
    wt[idx] = f2bf(w[k * 64 + c]);
}

// ---------- kernel 1: fused QKV projection ----------
// 8 waves/block; waves split N: wave w -> rows (w&3)*16, cols (w>>2)*96.
// Double-buffered LDS, global_load_lds staging, XOR-swizzled layouts.
// per buffer: xs f32 [64][64] (16KB, 16B-granule swizzle (row&15)<<4)
//             wst bf16 [192][64] (24KB, swizzle (row&7)<<4) at offset 16384
__global__ __launch_bounds__(512) void qkv_kernel(const float* __restrict__ x,
        const unsigned short* __restrict__ wt,
        unsigned short* __restrict__ kh,
        unsigned short* __restrict__ qh,
        unsigned short* __restrict__ vt) {
    __shared__ __attribute__((aligned(16))) char smem[2][40960];
    const int tid = threadIdx.x;
    const int wid = tid >> 6, lane = tid & 63;
    const int lq = lane & 15, g = lane >> 4;
    const int row0 = blockIdx.x * 64;
    const char* xg = (const char*)x;
    const char* wtg = (const char*)wt;

    f32x4 acc[6] = {};

    // stage tile k0 into buffer buf
    auto stage = [&](char* buf, int k0) {
        #pragma unroll
        for (int R = 0; R < 2; ++R) {                  // x: 16KB = 2 rounds
            int o = R * 8192 + wid * 1024;
            int ob = o + lane * 16;
            int row = ob >> 8, inrow = ob & 255;
            int src = inrow ^ ((row & 15) << 4);
            GLOAD16(xg + ((size_t)(row0 + row) * 4096 + (size_t)k0 * 4 + src), buf + o);
        }
        #pragma unroll
        for (int R = 0; R < 3; ++R) {                  // wt: 24KB = 3 rounds
            int o = R * 8192 + wid * 1024;
            int ob = o + lane * 16;
            int row = ob >> 7, inrow = ob & 127;
            int src = inrow ^ ((row & 7) << 4);
            GLOAD16(wtg + ((size_t)row * 2048 + (size_t)k0 * 2 + src), buf + 16384 + o);
        }
    };

    stage(smem[0], 0);
    asm volatile("s_waitcnt vmcnt(0)" ::: "memory");
    __syncthreads();

    for (int t = 0; t < 16; ++t) {
        char* cur = smem[t & 1];
        if (t < 15) stage(smem[(t + 1) & 1], (t + 1) * 64);

        const char* xb = cur;
        const char* wb = cur + 16384;
        // A fragments (x rows, f32 -> bf16)
        bf16x8 a[2];
        #pragma unroll
        for (int ks = 0; ks < 2; ++ks) {
            int row = (wid & 3) * 16 + lq;
            int kb0 = ks * 128 + g * 32;
            float4 f0 = *(const float4*)(xb + row * 256 + (kb0 ^ ((row & 15) << 4)));
            float4 f1 = *(const float4*)(xb + row * 256 + ((kb0 + 16) ^ ((row & 15) << 4)));
            union { unsigned short u[8]; bf16x8 v; } u;
            u.u[0] = f2bf(f0.x); u.u[1] = f2bf(f0.y); u.u[2] = f2bf(f0.z); u.u[3] = f2bf(f0.w);
            u.u[4] = f2bf(f1.x); u.u[5] = f2bf(f1.y); u.u[6] = f2bf(f1.z); u.u[7] = f2bf(f1.w);
            a[ks] = u.v;
        }
        #pragma unroll
        for (int j = 0; j < 6; ++j) {
            int row = (wid >> 2) * 96 + j * 16 + lq;
            #pragma unroll
            for (int ks = 0; ks < 2; ++ks) {
                int kb = ks * 64 + g * 16;
                bf16x8 bfrag = *(const bf16x8*)(wb + row * 128 + (kb ^ ((row & 7) << 4)));
                acc[j] = __builtin_amdgcn_mfma_f32_16x16x32_bf16(a[ks], bfrag, acc[j], 0, 0, 0);
            }
        }
        asm volatile("s_waitcnt vmcnt(0)" ::: "memory");
        __syncthreads();
    }

    // epilogue: D layout col=lane&15, row=(lane>>4)*4+reg
    #pragma unroll
    for (int j = 0; j < 6; ++j) {
        int col = (wid >> 2) * 96 + j * 16 + lq;
        int m = col >> 6, h = col & 63;
        #pragma unroll
        for (int r = 0; r < 4; ++r) {
            int grow = row0 + (wid & 3) * 16 + g * 4 + r;
            float val = acc[j][r];
            if (m == 0) {
                kh[(size_t)grow * H_ + h] = f2bf(val);
            } else if (m == 1) {
                qh[(size_t)grow * H_ + h] = f2bf(val * 0.03125f);  // C^-0.5
            } else {
                int bb = grow >> 11, t = grow & (T_ - 1);
                vt[((size_t)bb * H_ + h) * T_ + t] = f2bf(val);
            }
        }
    }
}

// ---------- kernel 2: causal flash attention, 1 wave per (16 q-rows x s-chunk) ----------
// split mode: s split into 512-wide chunks; partial (O,m,l) -> po/pml, combined later.
__global__ __launch_bounds__(64) void attn_kernel(const unsigned short* __restrict__ kh,
        const unsigned short* __restrict__ qh,
        const unsigned short* __restrict__ vt,
        float* __restrict__ out,
        float* __restrict__ po, float* __restrict__ pml, int split) {
    __shared__ unsigned short p_lds[16][40];  // [q][s] bf16, padded row 80B
    int b, qi, c, nch;
    if (split) {
        b = blockIdx.x >> 9; int rem = blockIdx.x & 511;
        qi = 127 - (rem >> 2); c = rem & 3;
        nch = (qi + 32) >> 5;                 // ceil((qi*16+16)/512)
        if (c >= nch) return;
    } else {
        b = blockIdx.x >> 7; qi = 127 - (blockIdx.x & 127); c = 0; nch = 1;
    }
    const int lane = threadIdx.x;
    const int lq = lane & 15, g = lane >> 4;
    const int q0 = qi * 16;
    const int sbeg = c << 9;
    const int s_hi = q0 + 16;
    const int send = (split && (sbeg + 512) < s_hi) ? (sbeg + 512) : s_hi;

    const unsigned short* khb = kh + (size_t)b * T_ * H_;
    const unsigned short* qhb = qh + (size_t)b * T_ * H_;
    const unsigned short* vtb = vt + (size_t)b * H_ * T_;

    bf16x8 qf0 = *(const bf16x8*)(qhb + (q0 + lq) * H_ + g * 8);
    bf16x8 qf1 = *(const bf16x8*)(qhb + (q0 + lq) * H_ + 32 + g * 8);

    float m_run = -1e30f, l_run = 0.f;
    f32x4 o[4] = {};

    const int q_glob = q0 + lq;
    for (int s0 = sbeg; s0 < send; s0 += 32) {
        const bool t1 = (s0 + 16) < send;
        f32x4 sa0 = {0.f, 0.f, 0.f, 0.f};
        f32x4 sa1 = {0.f, 0.f, 0.f, 0.f};
        __builtin_amdgcn_s_setprio(1);
        {
            bf16x8 k00 = *(const bf16x8*)(khb + (s0 + lq) * H_ + g * 8);
            bf16x8 k01 = *(const bf16x8*)(khb + (s0 + lq) * H_ + 32 + g * 8);
            sa0 = __builtin_amdgcn_mfma_f32_16x16x32_bf16(k00, qf0, sa0, 0, 0, 0);
            sa0 = __builtin_amdgcn_mfma_f32_16x16x32_bf16(k01, qf1, sa0, 0, 0, 0);
        }
        if (t1) {
            bf16x8 k10 = *(const bf16x8*)(khb + (s0 + 16 + lq) * H_ + g * 8);
            bf16x8 k11 = *(const bf16x8*)(khb + (s0 + 16 + lq) * H_ + 32 + g * 8);
            sa1 = __builtin_amdgcn_mfma_f32_16x16x32_bf16(k10, qf0, sa1, 0, 0, 0);
            sa1 = __builtin_amdgcn_mfma_f32_16x16x32_bf16(k11, qf1, sa1, 0, 0, 0);
        }
        __builtin_amdgcn_s_setprio(0);
        // online softmax: per-lane q = lq, s = s0 + tile*16 + g*4 + r
        float p0[4], p1[4];
        float smax = -1e30f;
        #pragma unroll
        for (int r = 0; r < 4; ++r) {
            int sg0 = s0 + g * 4 + r;
            int sg1 = s0 + 16 + g * 4 + r;
            p0[r] = (sg0 <= q_glob) ? sa0[r] : -1e30f;
            p1[r] = (t1 && sg1 <= q_glob) ? sa1[r] : -1e30f;
            smax = fmaxf(smax, fmaxf(p0[r], p1[r]));
        }
        smax = fmaxf(smax, __shfl_xor(smax, 16));
        smax = fmaxf(smax, __shfl_xor(smax, 32));
        const float m_new = fmaxf(m_run, smax);
        const float alpha = __expf(m_run - m_new);
        float lsum = 0.f;
        #pragma unroll
        for (int r = 0; r < 4; ++r) {
            p0[r] = __expf(p0[r] - m_new);
            p1[r] = __expf(p1[r] - m_new);
            lsum += p0[r] + p1[r];
        }
        lsum += __shfl_xor(lsum, 16);
        lsum += __shfl_xor(lsum, 32);
        l_run = l_run * alpha + lsum;
        m_run = m_new;
        #pragma unroll
        for (int hc = 0; hc < 4; ++hc) o[hc] *= alpha;

        *(unsigned*)&p_lds[lq][g * 4]          = (unsigned)f2bf(p0[0]) | ((unsigned)f2bf(p0[1]) << 16);
        *(unsigned*)&p_lds[lq][g * 4 + 2]      = (unsigned)f2bf(p0[2]) | ((unsigned)f2bf(p0[3]) << 16);
        *(unsigned*)&p_lds[lq][16 + g * 4]     = (unsigned)f2bf(p1[0]) | ((unsigned)f2bf(p1[1]) << 16);
        *(unsigned*)&p_lds[lq][16 + g * 4 + 2] = (unsigned)f2bf(p1[2]) | ((unsigned)f2bf(p1[3]) << 16);

        bf16x8 pb = *(const bf16x8*)&p_lds[lq][g * 8];
        __builtin_amdgcn_s_setprio(1);
        #pragma unroll
        for (int hc = 0; hc < 4; ++hc) {
            bf16x8 vf = *(const bf16x8*)(vtb + (size_t)(hc * 16 + lq) * T_ + s0 + g * 8);
            o[hc] = __builtin_amdgcn_mfma_f32_16x16x32_bf16(vf, pb, o[hc], 0, 0, 0);
        }
        __builtin_amdgcn_s_setprio(0);
    }

    if (nch == 1) {
        const float inv_l = 1.0f / l_run;
        float* ob = out + ((size_t)b * T_ + q0 + lq) * H_;
        #pragma unroll
        for (int hc = 0; hc < 4; ++hc)
            #pragma unroll
            for (int r = 0; r < 4; ++r)
                ob[hc * 16 + g * 4 + r] = o[hc][r] * inv_l;
    } else {
        int slot = (b * 128 + qi) * 4 + c;
        float* poS = po + (size_t)slot * 1024;
        #pragma unroll
        for (int hc = 0; hc < 4; ++hc)
            #pragma unroll
            for (int r = 0; r < 4; ++r)
                poS[(size_t)lq * 64 + hc * 16 + g * 4 + r] = o[hc][r];
        if (g == 0) {
            pml[slot * 16 + lq] = m_run;
            pml[65536 + slot * 16 + lq] = l_run;
        }
    }
}

// ---------- kernel 3: combine split-s partials (qi >= 32 only) ----------
__global__ __launch_bounds__(256) void combine_kernel(const float* __restrict__ po,
        const float* __restrict__ pml, float* __restrict__ out) {
    int b = blockIdx.x / 96, qi = 32 + blockIdx.x % 96;
    int nch = (qi + 32) >> 5;
    int r0 = threadIdx.x >> 6;
    int h = threadIdx.x & 63;
    int base_slot = (b * 128 + qi) * 4;
    for (int r = r0; r < 16; r += 4) {
        float m = -1e30f;
        for (int cc = 0; cc < nch; ++cc)
            m = fmaxf(m, pml[(base_slot + cc) * 16 + r]);
        float lsum = 0.f, osum = 0.f;
        for (int cc = 0; cc < nch; ++cc) {
            float w = __expf(pml[(base_slot + cc) * 16 + r] - m);
            lsum += pml[65536 + (base_slot + cc) * 16 + r] * w;
            osum += po[(size_t)(base_slot + cc) * 1024 + r * 64 + h] * w;
        }
        out[((size_t)b * T_ + qi * 16 + r) * H_ + h] = osum / lsum;
    }
}

extern "C" void kernel_launch(void* const* d_in, const int* in_sizes, int n_in,
                              void* d_out, int out_size, void* d_ws, size_t ws_size,
                              hipStream_t stream) {
    const float* x  = (const float*)d_in[0];
    const float* wk = (const float*)d_in[1];
    const float* wq = (const float*)d_in[2];
    const float* wv = (const float*)d_in[3];
    float* out = (float*)d_out;

    char* ws = (char*)d_ws;
    unsigned short* kh = (unsigned short*)(ws);                            // 2 MB
    unsigned short* qh = (unsigned short*)(ws + (size_t)2 * 1024 * 1024);  // 2 MB
    unsigned short* vt = (unsigned short*)(ws + (size_t)4 * 1024 * 1024);  // 2 MB
    unsigned short* wt = (unsigned short*)(ws + (size_t)6 * 1024 * 1024);  // 384 KB
    float* po  = (float*)(ws + (size_t)8 * 1024 * 1024);                   // 16 MB
    float* pml = (float*)(ws + (size_t)24 * 1024 * 1024);                  // 512 KB

    const bool split = ws_size >= (size_t)26 * 1024 * 1024;

    wtrans_kernel<<<dim3(768), dim3(256), 0, stream>>>(wk, wq, wv, wt);
    qkv_kernel<<<dim3(256), dim3(512), 0, stream>>>(x, wt, kh, qh, vt);
    attn_kernel<<<dim3(split ? 4096 : 1024), dim3(64), 0, stream>>>(kh, qh, vt, out, po, pml, split ? 1 : 0);
    if (split)
        combine_kernel<<<dim3(768), dim3(256), 0, stream>>>(po, pml, out);
}

// Round 3
// 83.255 us; speedup vs baseline: 1.7205x; 1.2516x over previous
//
#include <hip/hip_runtime.h>
#include <hip/hip_bf16.h>

#define B_ 8
#define T_ 2048
#define C_ 1024
#define H_ 64

typedef __bf16 bf16x8 __attribute__((ext_vector_type(8)));
typedef float f32x4 __attribute__((ext_vector_type(4)));

__device__ __forceinline__ unsigned short f2bf(float f) {
    union { float f; unsigned u; } v; v.f = f;
    unsigned u = v.u;
    u += 0x7fffu + ((u >> 16) & 1u);   // round-to-nearest-even
    return (unsigned short)(u >> 16);
}

#define GLOAD16(g, l) __builtin_amdgcn_global_load_lds( \
    (const __attribute__((address_space(1))) void*)(g), \
    (__attribute__((address_space(3))) void*)(l), 16, 0, 0)

#define MFMA16(a, b, c) __builtin_amdgcn_mfma_f32_16x16x32_bf16(a, b, c, 0, 0, 0)

// ---------- kernel 0: transpose+convert weights into wt[192][1024] bf16 ----------
__global__ void wtrans_kernel(const float* __restrict__ wk,
                              const float* __restrict__ wq,
                              const float* __restrict__ wv,
                              unsigned short* __restrict__ wt) {
    int idx = blockIdx.x * 256 + threadIdx.x;   // 192*1024 total
    int n = idx >> 10, k = idx & 1023;
    int m = n >> 6, c = n & 63;
    const float* w = (m == 0) ? wk : (m == 1) ? wq : wv;
    wt[idx] = f2bf(w[k * 64 + c]);
}

// ---------- kernel 1: fused QKV projection (unchanged from round 1) ----------
__global__ __launch_bounds__(512) void qkv_kernel(const float* __restrict__ x,
        const unsigned short* __restrict__ wt,
        unsigned short* __restrict__ kh,
        unsigned short* __restrict__ qh,
        unsigned short* __restrict__ vt) {
    __shared__ __attribute__((aligned(16))) char smem[2][40960];
    const int tid = threadIdx.x;
    const int wid = tid >> 6, lane = tid & 63;
    const int lq = lane & 15, g = lane >> 4;
    const int row0 = blockIdx.x * 64;
    const char* xg = (const char*)x;
    const char* wtg = (const char*)wt;

    f32x4 acc[6] = {};

    auto stage = [&](char* buf, int k0) {
        #pragma unroll
        for (int R = 0; R < 2; ++R) {
            int o = R * 8192 + wid * 1024;
            int ob = o + lane * 16;
            int row = ob >> 8, inrow = ob & 255;
            int src = inrow ^ ((row & 15) << 4);
            GLOAD16(xg + ((size_t)(row0 + row) * 4096 + (size_t)k0 * 4 + src), buf + o);
        }
        #pragma unroll
        for (int R = 0; R < 3; ++R) {
            int o = R * 8192 + wid * 1024;
            int ob = o + lane * 16;
            int row = ob >> 7, inrow = ob & 127;
            int src = inrow ^ ((row & 7) << 4);
            GLOAD16(wtg + ((size_t)row * 2048 + (size_t)k0 * 2 + src), buf + 16384 + o);
        }
    };

    stage(smem[0], 0);
    asm volatile("s_waitcnt vmcnt(0)" ::: "memory");
    __syncthreads();

    for (int t = 0; t < 16; ++t) {
        char* cur = smem[t & 1];
        if (t < 15) stage(smem[(t + 1) & 1], (t + 1) * 64);

        const char* xb = cur;
        const char* wb = cur + 16384;
        bf16x8 a[2];
        #pragma unroll
        for (int ks = 0; ks < 2; ++ks) {
            int row = (wid & 3) * 16 + lq;
            int kb0 = ks * 128 + g * 32;
            float4 f0 = *(const float4*)(xb + row * 256 + (kb0 ^ ((row & 15) << 4)));
            float4 f1 = *(const float4*)(xb + row * 256 + ((kb0 + 16) ^ ((row & 15) << 4)));
            union { unsigned short u[8]; bf16x8 v; } u;
            u.u[0] = f2bf(f0.x); u.u[1] = f2bf(f0.y); u.u[2] = f2bf(f0.z); u.u[3] = f2bf(f0.w);
            u.u[4] = f2bf(f1.x); u.u[5] = f2bf(f1.y); u.u[6] = f2bf(f1.z); u.u[7] = f2bf(f1.w);
            a[ks] = u.v;
        }
        #pragma unroll
        for (int j = 0; j < 6; ++j) {
            int row = (wid >> 2) * 96 + j * 16 + lq;
            #pragma unroll
            for (int ks = 0; ks < 2; ++ks) {
                int kb = ks * 64 + g * 16;
                bf16x8 bfrag = *(const bf16x8*)(wb + row * 128 + (kb ^ ((row & 7) << 4)));
                acc[j] = MFMA16(a[ks], bfrag, acc[j]);
            }
        }
        asm volatile("s_waitcnt vmcnt(0)" ::: "memory");
        __syncthreads();
    }

    #pragma unroll
    for (int j = 0; j < 6; ++j) {
        int col = (wid >> 2) * 96 + j * 16 + lq;
        int m = col >> 6, h = col & 63;
        #pragma unroll
        for (int r = 0; r < 4; ++r) {
            int grow = row0 + (wid & 3) * 16 + g * 4 + r;
            float val = acc[j][r];
            if (m == 0) {
                kh[(size_t)grow * H_ + h] = f2bf(val);
            } else if (m == 1) {
                qh[(size_t)grow * H_ + h] = f2bf(val * 0.03125f);  // C^-0.5
            } else {
                int bb = grow >> 11, t = grow & (T_ - 1);
                vt[((size_t)bb * H_ + h) * T_ + t] = f2bf(val);
            }
        }
    }
}

// ---------- kernel 2: causal flash attention v2 ----------
// 256-thread blocks (4 waves). Block = 64 q-rows (wave w -> rows qt*64+w*16..+16).
// KVBLK=64, K/V double-buffered in LDS via global_load_lds (pre-swizzled source).
// Optional s-split into 512-wide chunks (partials combined by combine_kernel).
__global__ __launch_bounds__(256) void attn_kernel(const unsigned short* __restrict__ kh,
        const unsigned short* __restrict__ qh,
        const unsigned short* __restrict__ vt,
        float* __restrict__ out,
        float* __restrict__ po, float* __restrict__ pml, int split) {
    __shared__ __attribute__((aligned(16))) char kv[2][16384];   // K 8KB + V 8KB per buf
    __shared__ __attribute__((aligned(16))) char pl[4][2048];    // per-wave P tile [16 q][64 s] bf16
    const int tid = threadIdx.x;
    const int wid = tid >> 6, lane = tid & 63;
    const int lq = lane & 15, g = lane >> 4;

    int b, qt, c, nch;
    if (split) {
        int qtc = blockIdx.x >> 3; b = blockIdx.x & 7;
        qt = 31 - (qtc >> 2); c = qtc & 3;
        nch = (qt + 8) >> 3;          // ceil((qt*64+64)/512)
        if (c >= nch) return;
    } else {
        b = blockIdx.x & 7; qt = 31 - (blockIdx.x >> 3); c = 0; nch = 1;
    }
    const int qw = qt * 64 + wid * 16;
    const int q_glob = qw + lq;
    const int s_end_blk = qt * 64 + 64;
    const int sbeg = c << 9;
    const int send = (split && sbeg + 512 < s_end_blk) ? sbeg + 512 : s_end_blk;
    const int nt = (send - sbeg) >> 6;

    const char* khb = (const char*)kh + (size_t)b * T_ * H_ * 2;
    const char* vtb = (const char*)vt + (size_t)b * H_ * T_ * 2;
    const unsigned short* qhb = qh + (size_t)b * T_ * H_;

    bf16x8 qf0 = *(const bf16x8*)(qhb + (qw + lq) * H_ + g * 8);
    bf16x8 qf1 = *(const bf16x8*)(qhb + (qw + lq) * H_ + 32 + g * 8);

    auto stage = [&](char* buf, int s0) {
        #pragma unroll
        for (int R = 0; R < 2; ++R) {              // K tile: rows = s, 128B each
            int o = R * 4096 + wid * 1024;
            int ob = o + lane * 16;
            int row = ob >> 7, inrow = ob & 127;
            int src = inrow ^ ((row & 7) << 4);
            GLOAD16(khb + (size_t)(s0 + row) * 128 + src, buf + o);
        }
        #pragma unroll
        for (int R = 0; R < 2; ++R) {              // V tile: rows = h, 128B window of vt row
            int o = R * 4096 + wid * 1024;
            int ob = o + lane * 16;
            int row = ob >> 7, inrow = ob & 127;
            int src = inrow ^ ((row & 7) << 4);
            GLOAD16(vtb + (size_t)row * 4096 + (size_t)s0 * 2 + src, buf + 8192 + o);
        }
    };

    float m_run = -1e30f, l_run = 0.f;
    f32x4 o_acc[4] = {};
    char* pbase = pl[wid];
    const int pswz = (lq & 7) << 4;

    stage(kv[0], sbeg);
    asm volatile("s_waitcnt vmcnt(0)" ::: "memory");
    __syncthreads();

    for (int t = 0; t < nt; ++t) {
        const int s0 = sbeg + t * 64;
        char* cur = kv[t & 1];
        if (t + 1 < nt) stage(kv[(t + 1) & 1], s0 + 64);
        const bool domask = (s0 + 64 == s_end_blk);   // diagonal step

        // QK^T: sa[st] = K[s0+st*16..+16][:] . Q^T
        f32x4 sa[4];
        __builtin_amdgcn_s_setprio(1);
        #pragma unroll
        for (int st = 0; st < 4; ++st) {
            int row = st * 16 + lq;
            int swz = (row & 7) << 4;
            f32x4 a = {};
            bf16x8 k0 = *(const bf16x8*)(cur + row * 128 + ((g * 16) ^ swz));
            bf16x8 k1 = *(const bf16x8*)(cur + row * 128 + ((64 + g * 16) ^ swz));
            a = MFMA16(k0, qf0, a);
            a = MFMA16(k1, qf1, a);
            sa[st] = a;
        }
        __builtin_amdgcn_s_setprio(0);

        // online softmax (per-lane q = lq; s = s0 + st*16 + g*4 + r)
        float p[4][4];
        float smax = -1e30f;
        #pragma unroll
        for (int st = 0; st < 4; ++st)
            #pragma unroll
            for (int r = 0; r < 4; ++r) {
                float v = sa[st][r];
                if (domask) {
                    int sg = s0 + st * 16 + g * 4 + r;
                    v = (sg <= q_glob) ? v : -1e30f;
                }
                p[st][r] = v;
                smax = fmaxf(smax, v);
            }
        smax = fmaxf(smax, __shfl_xor(smax, 16));
        smax = fmaxf(smax, __shfl_xor(smax, 32));
        const float m_new = fmaxf(m_run, smax);
        const float alpha = __expf(m_run - m_new);
        float lsum = 0.f;
        #pragma unroll
        for (int st = 0; st < 4; ++st)
            #pragma unroll
            for (int r = 0; r < 4; ++r) {
                p[st][r] = __expf(p[st][r] - m_new);
                lsum += p[st][r];
            }
        lsum += __shfl_xor(lsum, 16);
        lsum += __shfl_xor(lsum, 32);
        l_run = l_run * alpha + lsum;
        m_run = m_new;
        #pragma unroll
        for (int hc = 0; hc < 4; ++hc) o_acc[hc] *= alpha;

        // write P (bf16) to per-wave LDS tile, swizzled rows
        #pragma unroll
        for (int st = 0; st < 4; ++st) {
            union { unsigned short u[4]; uint2 d; } pk;
            pk.u[0] = f2bf(p[st][0]); pk.u[1] = f2bf(p[st][1]);
            pk.u[2] = f2bf(p[st][2]); pk.u[3] = f2bf(p[st][3]);
            *(uint2*)(pbase + lq * 128 + ((st * 32 + g * 8) ^ pswz)) = pk.d;
        }

        // PV: o_acc[hc] += V^T[hc*16+lq][s0+ss*32..] . P^T
        __builtin_amdgcn_s_setprio(1);
        #pragma unroll
        for (int hc = 0; hc < 4; ++hc) {
            int row = hc * 16 + lq;
            int swz = (row & 7) << 4;
            #pragma unroll
            for (int ss = 0; ss < 2; ++ss) {
                bf16x8 vf = *(const bf16x8*)(cur + 8192 + row * 128 + ((ss * 64 + g * 16) ^ swz));
                bf16x8 pb = *(const bf16x8*)(pbase + lq * 128 + ((ss * 64 + g * 16) ^ pswz));
                o_acc[hc] = MFMA16(vf, pb, o_acc[hc]);
            }
        }
        __builtin_amdgcn_s_setprio(0);

        asm volatile("s_waitcnt vmcnt(0)" ::: "memory");
        __syncthreads();
    }

    if (nch == 1) {
        const float inv_l = 1.0f / l_run;
        float* ob = out + ((size_t)b * T_ + qw + lq) * H_;
        #pragma unroll
        for (int hc = 0; hc < 4; ++hc)
            #pragma unroll
            for (int r = 0; r < 4; ++r)
                ob[hc * 16 + g * 4 + r] = o_acc[hc][r] * inv_l;
    } else {
        const int slot = (b * 32 + qt) * 4 + c;
        float* poS = po + (size_t)slot * 4096;
        const int row = wid * 16 + lq;
        #pragma unroll
        for (int hc = 0; hc < 4; ++hc)
            #pragma unroll
            for (int r = 0; r < 4; ++r)
                poS[(size_t)row * 64 + hc * 16 + g * 4 + r] = o_acc[hc][r];
        if (g == 0) {
            pml[slot * 64 + row] = m_run;
            pml[65536 + slot * 64 + row] = l_run;
        }
    }
}

// ---------- kernel 3: combine split-s partials (qt >= 8 only) ----------
__global__ __launch_bounds__(256) void combine_kernel(const float* __restrict__ po,
        const float* __restrict__ pml, float* __restrict__ out) {
    int b = blockIdx.x / 24, qt = 8 + blockIdx.x % 24;
    int nch = (qt + 8) >> 3;
    int r0 = threadIdx.x >> 6;
    int h = threadIdx.x & 63;
    int base_slot = (b * 32 + qt) * 4;
    for (int r = r0; r < 64; r += 4) {
        float m = -1e30f;
        for (int cc = 0; cc < nch; ++cc)
            m = fmaxf(m, pml[(base_slot + cc) * 64 + r]);
        float lsum = 0.f, osum = 0.f;
        for (int cc = 0; cc < nch; ++cc) {
            float w = __expf(pml[(base_slot + cc) * 64 + r] - m);
            lsum += pml[65536 + (base_slot + cc) * 64 + r] * w;
            osum += po[(size_t)(base_slot + cc) * 4096 + r * 64 + h] * w;
        }
        out[((size_t)b * T_ + qt * 64 + r) * H_ + h] = osum / lsum;
    }
}

extern "C" void kernel_launch(void* const* d_in, const int* in_sizes, int n_in,
                              void* d_out, int out_size, void* d_ws, size_t ws_size,
                              hipStream_t stream) {
    const float* x  = (const float*)d_in[0];
    const float* wk = (const float*)d_in[1];
    const float* wq = (const float*)d_in[2];
    const float* wv = (const float*)d_in[3];
    float* out = (float*)d_out;

    char* ws = (char*)d_ws;
    unsigned short* kh = (unsigned short*)(ws);                            // 2 MB
    unsigned short* qh = (unsigned short*)(ws + (size_t)2 * 1024 * 1024);  // 2 MB
    unsigned short* vt = (unsigned short*)(ws + (size_t)4 * 1024 * 1024);  // 2 MB
    unsigned short* wt = (unsigned short*)(ws + (size_t)6 * 1024 * 1024);  // 384 KB
    float* po  = (float*)(ws + (size_t)8 * 1024 * 1024);                   // 16 MB
    float* pml = (float*)(ws + (size_t)24 * 1024 * 1024);                  // 512 KB

    const bool split = ws_size >= (size_t)25 * 1024 * 1024;

    wtrans_kernel<<<dim3(768), dim3(256), 0, stream>>>(wk, wq, wv, wt);
    qkv_kernel<<<dim3(256), dim3(512), 0, stream>>>(x, wt, kh, qh, vt);
    attn_kernel<<<dim3(split ? 1024 : 256), dim3(256), 0, stream>>>(kh, qh, vt, out, po, pml, split ? 1 : 0);
    if (split)
        combine_kernel<<<dim3(192), dim3(256), 0, stream>>>(po, pml, out);
}